// Round 9
// baseline (198.185 us; speedup 1.0000x reference)
//
#include <hip/hip_runtime.h>
#include <hip/hip_bf16.h>

#define NPT    16384
#define TOTP   32768          // B*N
#define FD     128
#define CHK    32             // output points per fused block
#define CPB    (NPT/CHK)      // 512
#define GRID   (2*CPB)        // 1024 = 4 blocks/CU exactly
#define EXT    (CHK+24)       // 56 position rows (A-12 .. Bp+12)
#define FQM    (CHK+21)       // 53 fproj rows    (A-10 .. Bp+11)

// prep buffer layout (u16 units)
#define OFF_WFA 0             // Wf2 frags   [wid][ntg][kk]        4*2*4*512 = 16384
#define OFF_WFB 16384         // W0[3:] frags same                  16384
#define OFF_WB  32768         // Wb frags    [wid][layer][ntg][kk] 4*2*2*4*512 = 65536
#define OFF_WO  98304         // Wo frags    [kk]                   4*512 = 2048
#define PREP_TOT 100352

typedef unsigned short u16;
typedef __attribute__((ext_vector_type(8))) short bf16x8;
typedef __attribute__((ext_vector_type(4))) float f32x4;

__device__ __forceinline__ float bf2f(u16 u) {
    union { unsigned int i; float f; } v; v.i = ((unsigned int)u) << 16; return v.f;
}
__device__ __forceinline__ u16 f2bf(float f) {   // manual RNE (prep only)
    union { float f; unsigned int i; } v; v.f = f;
    unsigned int u = v.i;
    u = u + 0x7FFFu + ((u >> 16) & 1u);
    return (u16)(u >> 16);
}
__device__ __forceinline__ u16 f2bf_hw(float f) { // HW cvt (hot loops)
    __hip_bfloat16 h = __float2bfloat16(f);
    return *(u16*)&h;
}
// 32x128 bf16 tile, row stride 256B, XOR swizzle (conflict-free b128 col reads)
__device__ __forceinline__ int swz(int row, int colbyte) {
    return row*256 + (colbyte ^ ((row & 7) << 4));
}
// fproj LDS tile [FQM][128] bf16, same XOR swizzle (conflict-free for
// 4-rows x 32-consecutive-cols access; bijective within each 256B row)
__device__ __forceinline__ int fswz(int row, int col) {
    return row*256 + ((col*2) ^ ((row & 7) << 4));
}

// ---------------------------------------------------------------------------
// Build all weight fragments in bf16 fragment order (one thread per u16).
// Layout verified (rounds 6-8 passed with this prep).
// ---------------------------------------------------------------------------
__global__ __launch_bounds__(256) void prep_weights(
    const float* __restrict__ Wf2, const float* __restrict__ W0,
    const float* __restrict__ Wb,  const float* __restrict__ Wo,
    u16* __restrict__ W)
{
    int t = blockIdx.x*256 + threadIdx.x;
    if (t >= PREP_TOT) return;
    float val;
    if (t < OFF_WB) {                      // wfA / wfB regions (same geometry)
        int u = t & 16383;
        int e = u & 7, l = (u >> 3) & 63, kk = (u >> 9) & 3;
        int ntg = (u >> 11) & 1, wid = (u >> 12) & 3;
        int col = wid*32 + ntg*16 + (l & 15);
        int k   = kk*32 + (l >> 4)*8 + e;
        val = (t < OFF_WFB) ? Wf2[k*FD + col] : W0[(3+k)*FD + col];
    } else if (t < OFF_WO) {               // Wb frags
        int u = t - OFF_WB;
        int e = u & 7, l = (u >> 3) & 63, kk = (u >> 9) & 3;
        int ntg = (u >> 11) & 1, layer = (u >> 12) & 1, wid = (u >> 13) & 3;
        int col = wid*32 + ntg*16 + (l & 15);
        int k   = kk*32 + (l >> 4)*8 + e;
        val = Wb[layer*FD*FD + k*FD + col];
    } else {                               // Wo padded 128x16 (cols>=3 zero)
        int u = t - OFF_WO;
        int e = u & 7, l = (u >> 3) & 63, kk = (u >> 9) & 3;
        int l15 = l & 15;
        int k   = kk*32 + (l >> 4)*8 + e;
        val = (l15 < 3) ? Wo[k*3 + l15] : 0.f;
    }
    W[t] = f2bf(val);
}

// ---------------------------------------------------------------------------
// Fully fused: per-block fproj prologue (feature net on own halo) + 4 denoise
// steps, everything in LDS. Block owns CHK points + halo 12.
// (256,2): 256-VGPR budget — the empirically spill-free configuration.
// LDS = 40,160 B -> 4 blocks/CU.
// ---------------------------------------------------------------------------
__global__ __launch_bounds__(256, 2) void fused_all(
    const float* __restrict__ pcl, const float* __restrict__ Wf1,
    const float* __restrict__ bf1, const float* __restrict__ bf2,
    const float* __restrict__ W0,  const float* __restrict__ b0,
    const float* __restrict__ bb,  const float* __restrict__ bo,
    const u16* __restrict__ Wprep, float* __restrict__ out)
{
    __shared__ __align__(16) u16   fpl[FQM*128];   // fproj halo, swizzled
    __shared__ __align__(16) float X0l[EXT*3];     // original pcl (noisy)
    __shared__ __align__(16) float Xal[EXT*3];
    __shared__ __align__(16) float Xbl[EXT*3];
    __shared__ __align__(16) char  hA[8192];
    __shared__ __align__(16) char  hB[8192];
    __shared__ __align__(16) char  hC[8192];

    const int tid = threadIdx.x, wid = tid >> 6, l = tid & 63;
    const int l15 = l & 15, l4 = l >> 4;
    const int colb = wid * 32;

    const int blk = blockIdx.x;
    const int b = blk >> 9, cidx = blk & (CPB - 1);
    const int A = cidx * CHK;
    const int Bp = A + CHK - 1;
    const int elo  = (A - 12 < 0) ? 0 : A - 12;
    const int ehi  = (Bp + 12 > NPT-1) ? NPT-1 : Bp + 12;
    const int esz3 = (ehi - elo + 1) * 3;
    const int fqlo = (A - 10 < 0) ? 0 : A - 10;
    const int fqhi = (Bp + 11 > NPT-1) ? NPT-1 : Bp + 11;
    const int fqc  = fqhi - fqlo + 1;
    const size_t gb = (size_t)b * NPT;

    // ---- stage noisy positions ----
    for (int i = tid; i < esz3; i += 256) X0l[i] = pcl[(gb + elo)*3 + i];
    __syncthreads();

    // ================= fproj prologue (feature net on halo rows) ============
    {
        bf16x8 wfA[2][4], wfB[2][4];
        {
            const bf16x8* fa = (const bf16x8*)(Wprep + OFF_WFA);
            const bf16x8* fb = (const bf16x8*)(Wprep + OFF_WFB);
            #pragma unroll
            for (int ntg = 0; ntg < 2; ++ntg)
                #pragma unroll
                for (int kk = 0; kk < 4; ++kk) {
                    int fi = ((wid*2 + ntg)*4 + kk)*64 + l;
                    wfA[ntg][kk] = fa[fi];
                    wfB[ntg][kk] = fb[fi];
                }
        }
        float wf1c[3][2], bf1v[2], bf2v[2], b0v[2];
        #pragma unroll
        for (int ntg = 0; ntg < 2; ++ntg) {
            int col = colb + ntg*16 + l15;
            wf1c[0][ntg] = Wf1[0*FD+col];
            wf1c[1][ntg] = Wf1[1*FD+col];
            wf1c[2][ntg] = Wf1[2*FD+col];
            bf1v[ntg] = bf1[col]; bf2v[ntg] = bf2[col]; b0v[ntg] = b0[col];
        }
        const int nft = (fqc + 31) >> 5;
        for (int ft = 0; ft < nft; ++ft) {
            const int r0 = ft*32;
            // P0: T = relu(X @ Wf1 + bf1) -> hA
            #pragma unroll
            for (int rt = 0; rt < 2; ++rt)
                #pragma unroll
                for (int reg = 0; reg < 4; ++reg) {
                    int row = rt*16 + l4*4 + reg;
                    int q = fqlo + r0 + row; if (q > fqhi) q = fqhi;
                    int qe = (q - elo)*3;
                    float px = X0l[qe], py = X0l[qe+1], pz = X0l[qe+2];
                    #pragma unroll
                    for (int ntg = 0; ntg < 2; ++ntg) {
                        float tv = bf1v[ntg] + px*wf1c[0][ntg] + py*wf1c[1][ntg] + pz*wf1c[2][ntg];
                        tv = fmaxf(tv, 0.f);
                        int col = colb + ntg*16 + l15;
                        *(u16*)(hA + swz(row, col*2)) = f2bf_hw(tv);
                    }
                }
            __syncthreads();
            // P1: feat = T @ Wf2 + bf2 -> hB  (no relu)
            {
                bf16x8 a[2][4];
                #pragma unroll
                for (int rt = 0; rt < 2; ++rt)
                    #pragma unroll
                    for (int kk = 0; kk < 4; ++kk)
                        a[rt][kk] = *(const bf16x8*)(hA + swz(rt*16 + l15, kk*64 + l4*16));
                #pragma unroll
                for (int ntg = 0; ntg < 2; ++ntg) {
                    f32x4 acc0 = {bf2v[ntg],bf2v[ntg],bf2v[ntg],bf2v[ntg]};
                    f32x4 acc1 = acc0;
                    #pragma unroll
                    for (int kk = 0; kk < 4; ++kk) {
                        acc0 = __builtin_amdgcn_mfma_f32_16x16x32_bf16(a[0][kk], wfA[ntg][kk], acc0, 0,0,0);
                        acc1 = __builtin_amdgcn_mfma_f32_16x16x32_bf16(a[1][kk], wfA[ntg][kk], acc1, 0,0,0);
                    }
                    int col = colb + ntg*16 + l15;
                    #pragma unroll
                    for (int reg = 0; reg < 4; ++reg) {
                        *(u16*)(hB + swz(l4*4+reg,    col*2)) = f2bf_hw(acc0[reg]);
                        *(u16*)(hB + swz(16+l4*4+reg, col*2)) = f2bf_hw(acc1[reg]);
                    }
                }
            }
            __syncthreads();
            // P2: fpl = feat @ W0[3:] + b0  (guarded rows, swizzled store)
            {
                bf16x8 a[2][4];
                #pragma unroll
                for (int rt = 0; rt < 2; ++rt)
                    #pragma unroll
                    for (int kk = 0; kk < 4; ++kk)
                        a[rt][kk] = *(const bf16x8*)(hB + swz(rt*16 + l15, kk*64 + l4*16));
                #pragma unroll
                for (int ntg = 0; ntg < 2; ++ntg) {
                    f32x4 acc0 = {b0v[ntg],b0v[ntg],b0v[ntg],b0v[ntg]};
                    f32x4 acc1 = acc0;
                    #pragma unroll
                    for (int kk = 0; kk < 4; ++kk) {
                        acc0 = __builtin_amdgcn_mfma_f32_16x16x32_bf16(a[0][kk], wfB[ntg][kk], acc0, 0,0,0);
                        acc1 = __builtin_amdgcn_mfma_f32_16x16x32_bf16(a[1][kk], wfB[ntg][kk], acc1, 0,0,0);
                    }
                    int col = colb + ntg*16 + l15;
                    #pragma unroll
                    for (int reg = 0; reg < 4; ++reg) {
                        int ra = r0 + l4*4 + reg, rb = r0 + 16 + l4*4 + reg;
                        if (ra < fqc) *(u16*)((char*)fpl + fswz(ra, col)) = f2bf_hw(acc0[reg]);
                        if (rb < fqc) *(u16*)((char*)fpl + fswz(rb, col)) = f2bf_hw(acc1[reg]);
                    }
                }
            }
            __syncthreads();
        }
    }
    __builtin_amdgcn_sched_barrier(0);   // keep Wb/Wo frag loads AFTER prologue

    // ---- main weight fragments ----
    bf16x8 wfrag[2][2][4], wofrag[4];
    {
        const bf16x8* wb = (const bf16x8*)(Wprep + OFF_WB);
        #pragma unroll
        for (int layer = 0; layer < 2; ++layer)
            #pragma unroll
            for (int ntg = 0; ntg < 2; ++ntg)
                #pragma unroll
                for (int kk = 0; kk < 4; ++kk)
                    wfrag[layer][ntg][kk] = wb[(((wid*2+layer)*2+ntg)*4+kk)*64 + l];
        const bf16x8* wo = (const bf16x8*)(Wprep + OFF_WO);
        #pragma unroll
        for (int kk = 0; kk < 4; ++kk) wofrag[kk] = wo[kk*64 + l];
    }
    float w0c[3][2], bbv[2][2];
    #pragma unroll
    for (int ntg = 0; ntg < 2; ++ntg) {
        int col = colb + ntg*16 + l15;
        w0c[0][ntg] = W0[0*FD+col];
        w0c[1][ntg] = W0[1*FD+col];
        w0c[2][ntg] = W0[2*FD+col];
        bbv[0][ntg] = bb[col]; bbv[1][ntg] = bb[FD+col];
    }
    const float bol = (l15 < 3) ? bo[l15] : 0.f;

    auto do_step = [&](const float* curl, float* nxtl, float sval, int qlo, int qhi) {
        for (int i = tid; i < esz3; i += 256) nxtl[i] = curl[i];
        __syncthreads();
        const int nt_ = (qhi - qlo + 8) >> 3;
        for (int t = 0; t < nt_; ++t) {
            const int qbase = qlo + t*8;
            float hc[2][2][4];
            // ---- P0: layer0 -> hA ----
            #pragma unroll
            for (int rt = 0; rt < 2; ++rt) {
                int q = qbase + rt*4 + l4; if (q > qhi) q = qhi;
                int qe = (q - elo)*3;
                float nx = X0l[qe], ny = X0l[qe+1], nz = X0l[qe+2];
                float cx[4], cy[4], cz[4];
                #pragma unroll
                for (int k = 0; k < 4; ++k) {
                    int nb = q + k - 2;
                    nb = nb < 0 ? 0 : (nb > NPT-1 ? NPT-1 : nb);
                    int te = (nb - elo)*3;
                    cx[k] = curl[te]   - nx;
                    cy[k] = curl[te+1] - ny;
                    cz[k] = curl[te+2] - nz;
                }
                #pragma unroll
                for (int ntg = 0; ntg < 2; ++ntg) {
                    int col = colb + ntg*16 + l15;
                    float fp = bf2f(*(const u16*)((const char*)fpl + fswz(q - fqlo, col)));
                    #pragma unroll
                    for (int reg = 0; reg < 4; ++reg) {
                        float u = fp + cx[reg]*w0c[0][ntg] + cy[reg]*w0c[1][ntg] + cz[reg]*w0c[2][ntg];
                        u = fmaxf(u, 0.f);
                        hc[rt][ntg][reg] = u;
                        *(u16*)(hA + swz(rt*16 + l4*4 + reg, col*2)) = f2bf_hw(u);
                    }
                }
            }
            __syncthreads();
            // ---- P1: layer1 -> hB ----
            {
                bf16x8 a[2][4];
                #pragma unroll
                for (int rt = 0; rt < 2; ++rt)
                    #pragma unroll
                    for (int kk = 0; kk < 4; ++kk)
                        a[rt][kk] = *(const bf16x8*)(hA + swz(rt*16 + l15, kk*64 + l4*16));
                #pragma unroll
                for (int ntg = 0; ntg < 2; ++ntg) {
                    f32x4 acc0 = {bbv[0][ntg],bbv[0][ntg],bbv[0][ntg],bbv[0][ntg]};
                    f32x4 acc1 = acc0;
                    #pragma unroll
                    for (int kk = 0; kk < 4; ++kk) {
                        acc0 = __builtin_amdgcn_mfma_f32_16x16x32_bf16(a[0][kk], wfrag[0][ntg][kk], acc0, 0,0,0);
                        acc1 = __builtin_amdgcn_mfma_f32_16x16x32_bf16(a[1][kk], wfrag[0][ntg][kk], acc1, 0,0,0);
                    }
                    int col = colb + ntg*16 + l15;
                    #pragma unroll
                    for (int reg = 0; reg < 4; ++reg) {
                        hc[0][ntg][reg] += fmaxf(acc0[reg], 0.f);
                        hc[1][ntg][reg] += fmaxf(acc1[reg], 0.f);
                        *(u16*)(hB + swz(l4*4+reg,    col*2)) = f2bf_hw(hc[0][ntg][reg]);
                        *(u16*)(hB + swz(16+l4*4+reg, col*2)) = f2bf_hw(hc[1][ntg][reg]);
                    }
                }
            }
            __syncthreads();
            // ---- P2: layer2 -> hC ----
            {
                bf16x8 a[2][4];
                #pragma unroll
                for (int rt = 0; rt < 2; ++rt)
                    #pragma unroll
                    for (int kk = 0; kk < 4; ++kk)
                        a[rt][kk] = *(const bf16x8*)(hB + swz(rt*16 + l15, kk*64 + l4*16));
                #pragma unroll
                for (int ntg = 0; ntg < 2; ++ntg) {
                    f32x4 acc0 = {bbv[1][ntg],bbv[1][ntg],bbv[1][ntg],bbv[1][ntg]};
                    f32x4 acc1 = acc0;
                    #pragma unroll
                    for (int kk = 0; kk < 4; ++kk) {
                        acc0 = __builtin_amdgcn_mfma_f32_16x16x32_bf16(a[0][kk], wfrag[1][ntg][kk], acc0, 0,0,0);
                        acc1 = __builtin_amdgcn_mfma_f32_16x16x32_bf16(a[1][kk], wfrag[1][ntg][kk], acc1, 0,0,0);
                    }
                    int col = colb + ntg*16 + l15;
                    #pragma unroll
                    for (int reg = 0; reg < 4; ++reg) {
                        float h0 = hc[0][ntg][reg] + fmaxf(acc0[reg], 0.f);
                        float h1 = hc[1][ntg][reg] + fmaxf(acc1[reg], 0.f);
                        *(u16*)(hC + swz(l4*4+reg,    col*2)) = f2bf_hw(h0);
                        *(u16*)(hC + swz(16+l4*4+reg, col*2)) = f2bf_hw(h1);
                    }
                }
            }
            __syncthreads();
            // ---- P3: grad = h@Wo (+bo), LDS-atomic scatter (waves 0,1) ----
            if (wid < 2) {
                const int sub = wid;
                bf16x8 a[4];
                #pragma unroll
                for (int kk = 0; kk < 4; ++kk)
                    a[kk] = *(const bf16x8*)(hC + swz(sub*16 + l15, kk*64 + l4*16));
                f32x4 acc = {0.f,0.f,0.f,0.f};
                #pragma unroll
                for (int kk = 0; kk < 4; ++kk)
                    acc = __builtin_amdgcn_mfma_f32_16x16x32_bf16(a[kk], wofrag[kk], acc, 0,0,0);
                int q = qbase + sub*4 + l4;
                if (l15 < 3 && q <= qhi) {
                    #pragma unroll
                    for (int reg = 0; reg < 4; ++reg) {
                        int nb = q + reg - 2;
                        nb = nb < 0 ? 0 : (nb > NPT-1 ? NPT-1 : nb);
                        atomicAdd(&nxtl[(nb - elo)*3 + l15], sval*(acc[reg] + bol));
                    }
                }
            }
            // no barrier: next-tile P0 writes hA (not hC); P0-end barrier protects P1
        }
        __syncthreads();   // all scatters complete before next step reads nxtl
    };

    const int q1lo = fqlo,                 q1hi = fqhi;
    const int q2lo = (A-7 < 0) ? 0 : A-7,  q2hi = (Bp+8 > NPT-1) ? NPT-1 : Bp+8;
    const int q3lo = (A-4 < 0) ? 0 : A-4,  q3hi = (Bp+5 > NPT-1) ? NPT-1 : Bp+5;
    const int q4lo = (A-1 < 0) ? 0 : A-1,  q4hi = (Bp+2 > NPT-1) ? NPT-1 : Bp+2;

    do_step(X0l, Xal, 0.2f,      q1lo, q1hi);
    do_step(Xal, Xbl, 0.19f,     q2lo, q2hi);
    do_step(Xbl, Xal, 0.1805f,   q3lo, q3hi);
    do_step(Xal, Xbl, 0.171475f, q4lo, q4hi);

    for (int i = tid; i < CHK*3; i += 256)
        out[(gb + A)*3 + i] = Xbl[(A - elo)*3 + i];
}

extern "C" void kernel_launch(void* const* d_in, const int* in_sizes, int n_in,
                              void* d_out, int out_size, void* d_ws, size_t ws_size,
                              hipStream_t stream) {
    const float* pcl = (const float*)d_in[0];
    const float* Wf1 = (const float*)d_in[1];
    const float* bf1 = (const float*)d_in[2];
    const float* Wf2 = (const float*)d_in[3];
    const float* bf2 = (const float*)d_in[4];
    const float* W0  = (const float*)d_in[5];
    const float* b0  = (const float*)d_in[6];
    const float* Wb  = (const float*)d_in[7];
    const float* bb  = (const float*)d_in[8];
    const float* Wo  = (const float*)d_in[9];
    const float* bo  = (const float*)d_in[10];
    float* out = (float*)d_out;

    u16* Wprep = (u16*)d_ws;   // 200 KB

    prep_weights<<<(PREP_TOT+255)/256, 256, 0, stream>>>(Wf2, W0, Wb, Wo, Wprep);
    fused_all<<<GRID, 256, 0, stream>>>(pcl, Wf1, bf1, bf2, W0, b0, bb, bo, Wprep, out);
}

// Round 10
// 174.488 us; speedup vs baseline: 1.1358x; 1.1358x over previous
//
#include <hip/hip_runtime.h>
#include <hip/hip_bf16.h>

#define NPT    16384
#define TOTP   32768          // B*N
#define FD     128
#define CHK    64             // output points per fused block
#define CPB    (NPT/CHK)      // 256
#define GRID   (2*CPB)        // 512 = 2 blocks/CU exactly
#define EXT    (CHK+24)       // 88 position rows (A-12 .. Bp+12)
#define FQM    (CHK+21)       // 85 fproj rows    (A-10 .. Bp+11)

// prep buffer layout (u16 units)
#define OFF_WFA 0             // Wf2 frags   [wid][ntg][kk]        4*2*4*512 = 16384
#define OFF_WFB 16384         // W0[3:] frags same                  16384
#define OFF_WB  32768         // Wb frags    [wid][layer][ntg][kk] 4*2*2*4*512 = 65536
#define OFF_WO  98304         // Wo frags    [kk]                   4*512 = 2048
#define PREP_TOT 100352

typedef unsigned short u16;
typedef __attribute__((ext_vector_type(8))) short bf16x8;
typedef __attribute__((ext_vector_type(4))) float f32x4;

__device__ __forceinline__ float bf2f(u16 u) {
    union { unsigned int i; float f; } v; v.i = ((unsigned int)u) << 16; return v.f;
}
__device__ __forceinline__ u16 f2bf(float f) {   // manual RNE (prep only)
    union { float f; unsigned int i; } v; v.f = f;
    unsigned int u = v.i;
    u = u + 0x7FFFu + ((u >> 16) & 1u);
    return (u16)(u >> 16);
}
__device__ __forceinline__ u16 f2bf_hw(float f) { // HW cvt (hot loops)
    __hip_bfloat16 h = __float2bfloat16(f);
    return *(u16*)&h;
}
// 32x128 bf16 tile, row stride 256B, XOR swizzle (conflict-free b128 col reads)
__device__ __forceinline__ int swz(int row, int colbyte) {
    return row*256 + (colbyte ^ ((row & 7) << 4));
}
// fproj LDS tile [FQM][128] bf16, same XOR swizzle (verified round 9)
__device__ __forceinline__ int fswz(int row, int col) {
    return row*256 + ((col*2) ^ ((row & 7) << 4));
}

// ---------------------------------------------------------------------------
// Build all weight fragments in bf16 fragment order (one thread per u16).
// Layout verified (rounds 6-9 passed with this prep).
// ---------------------------------------------------------------------------
__global__ __launch_bounds__(256) void prep_weights(
    const float* __restrict__ Wf2, const float* __restrict__ W0,
    const float* __restrict__ Wb,  const float* __restrict__ Wo,
    u16* __restrict__ W)
{
    int t = blockIdx.x*256 + threadIdx.x;
    if (t >= PREP_TOT) return;
    float val;
    if (t < OFF_WB) {                      // wfA / wfB regions (same geometry)
        int u = t & 16383;
        int e = u & 7, l = (u >> 3) & 63, kk = (u >> 9) & 3;
        int ntg = (u >> 11) & 1, wid = (u >> 12) & 3;
        int col = wid*32 + ntg*16 + (l & 15);
        int k   = kk*32 + (l >> 4)*8 + e;
        val = (t < OFF_WFB) ? Wf2[k*FD + col] : W0[(3+k)*FD + col];
    } else if (t < OFF_WO) {               // Wb frags
        int u = t - OFF_WB;
        int e = u & 7, l = (u >> 3) & 63, kk = (u >> 9) & 3;
        int ntg = (u >> 11) & 1, layer = (u >> 12) & 1, wid = (u >> 13) & 3;
        int col = wid*32 + ntg*16 + (l & 15);
        int k   = kk*32 + (l >> 4)*8 + e;
        val = Wb[layer*FD*FD + k*FD + col];
    } else {                               // Wo padded 128x16 (cols>=3 zero)
        int u = t - OFF_WO;
        int e = u & 7, l = (u >> 3) & 63, kk = (u >> 9) & 3;
        int l15 = l & 15;
        int k   = kk*32 + (l >> 4)*8 + e;
        val = (l15 < 3) ? Wo[k*3 + l15] : 0.f;
    }
    W[t] = f2bf(val);
}

// ---------------------------------------------------------------------------
// Fully fused: per-block fproj prologue + 4 denoise steps, all in LDS.
// (256,2): 256-VGPR budget (spill-free). 2 q-tiles per barrier group (ILP).
// ---------------------------------------------------------------------------
__global__ __launch_bounds__(256, 2) void fused_all(
    const float* __restrict__ pcl, const float* __restrict__ Wf1,
    const float* __restrict__ bf1, const float* __restrict__ bf2,
    const float* __restrict__ W0,  const float* __restrict__ b0,
    const float* __restrict__ bb,  const float* __restrict__ bo,
    const u16* __restrict__ Wprep, float* __restrict__ out)
{
    __shared__ __align__(16) u16   fpl[FQM*128];   // fproj halo, swizzled (21.8 KB)
    __shared__ __align__(16) float X0l[EXT*3];
    __shared__ __align__(16) float Xal[EXT*3];
    __shared__ __align__(16) float Xbl[EXT*3];
    __shared__ __align__(16) char  hA0[8192];
    __shared__ __align__(16) char  hA1[8192];
    __shared__ __align__(16) char  hB0[8192];
    __shared__ __align__(16) char  hB1[8192];
    __shared__ __align__(16) char  hC0[8192];
    __shared__ __align__(16) char  hC1[8192];

    const int tid = threadIdx.x, wid = tid >> 6, l = tid & 63;
    const int l15 = l & 15, l4 = l >> 4;
    const int colb = wid * 32;

    const int blk = blockIdx.x;
    const int b = blk >> 8, cidx = blk & (CPB - 1);
    const int A = cidx * CHK;
    const int Bp = A + CHK - 1;
    const int elo  = (A - 12 < 0) ? 0 : A - 12;
    const int ehi  = (Bp + 12 > NPT-1) ? NPT-1 : Bp + 12;
    const int esz3 = (ehi - elo + 1) * 3;
    const int fqlo = (A - 10 < 0) ? 0 : A - 10;
    const int fqhi = (Bp + 11 > NPT-1) ? NPT-1 : Bp + 11;
    const int fqc  = fqhi - fqlo + 1;
    const size_t gb = (size_t)b * NPT;

    // ---- stage noisy positions ----
    for (int i = tid; i < esz3; i += 256) X0l[i] = pcl[(gb + elo)*3 + i];
    __syncthreads();

    // ================= fproj prologue (feature net on halo rows) ============
    {
        bf16x8 wfA[2][4], wfB[2][4];
        {
            const bf16x8* fa = (const bf16x8*)(Wprep + OFF_WFA);
            const bf16x8* fb = (const bf16x8*)(Wprep + OFF_WFB);
            #pragma unroll
            for (int ntg = 0; ntg < 2; ++ntg)
                #pragma unroll
                for (int kk = 0; kk < 4; ++kk) {
                    int fi = ((wid*2 + ntg)*4 + kk)*64 + l;
                    wfA[ntg][kk] = fa[fi];
                    wfB[ntg][kk] = fb[fi];
                }
        }
        float wf1c[3][2], bf1v[2], bf2v[2], b0v[2];
        #pragma unroll
        for (int ntg = 0; ntg < 2; ++ntg) {
            int col = colb + ntg*16 + l15;
            wf1c[0][ntg] = Wf1[0*FD+col];
            wf1c[1][ntg] = Wf1[1*FD+col];
            wf1c[2][ntg] = Wf1[2*FD+col];
            bf1v[ntg] = bf1[col]; bf2v[ntg] = bf2[col]; b0v[ntg] = b0[col];
        }
        const int nft = (fqc + 31) >> 5;
        for (int ft = 0; ft < nft; ++ft) {
            const int r0 = ft*32;
            // P0: T = relu(X @ Wf1 + bf1) -> hA0
            #pragma unroll
            for (int rt = 0; rt < 2; ++rt)
                #pragma unroll
                for (int reg = 0; reg < 4; ++reg) {
                    int row = rt*16 + l4*4 + reg;
                    int q = fqlo + r0 + row; if (q > fqhi) q = fqhi;
                    int qe = (q - elo)*3;
                    float px = X0l[qe], py = X0l[qe+1], pz = X0l[qe+2];
                    #pragma unroll
                    for (int ntg = 0; ntg < 2; ++ntg) {
                        float tv = bf1v[ntg] + px*wf1c[0][ntg] + py*wf1c[1][ntg] + pz*wf1c[2][ntg];
                        tv = fmaxf(tv, 0.f);
                        int col = colb + ntg*16 + l15;
                        *(u16*)(hA0 + swz(row, col*2)) = f2bf_hw(tv);
                    }
                }
            __syncthreads();
            // P1: feat = T @ Wf2 + bf2 -> hB0  (no relu)
            {
                bf16x8 a[2][4];
                #pragma unroll
                for (int rt = 0; rt < 2; ++rt)
                    #pragma unroll
                    for (int kk = 0; kk < 4; ++kk)
                        a[rt][kk] = *(const bf16x8*)(hA0 + swz(rt*16 + l15, kk*64 + l4*16));
                #pragma unroll
                for (int ntg = 0; ntg < 2; ++ntg) {
                    f32x4 acc0 = {bf2v[ntg],bf2v[ntg],bf2v[ntg],bf2v[ntg]};
                    f32x4 acc1 = acc0;
                    #pragma unroll
                    for (int kk = 0; kk < 4; ++kk) {
                        acc0 = __builtin_amdgcn_mfma_f32_16x16x32_bf16(a[0][kk], wfA[ntg][kk], acc0, 0,0,0);
                        acc1 = __builtin_amdgcn_mfma_f32_16x16x32_bf16(a[1][kk], wfA[ntg][kk], acc1, 0,0,0);
                    }
                    int col = colb + ntg*16 + l15;
                    #pragma unroll
                    for (int reg = 0; reg < 4; ++reg) {
                        *(u16*)(hB0 + swz(l4*4+reg,    col*2)) = f2bf_hw(acc0[reg]);
                        *(u16*)(hB0 + swz(16+l4*4+reg, col*2)) = f2bf_hw(acc1[reg]);
                    }
                }
            }
            __syncthreads();
            // P2: fpl = feat @ W0[3:] + b0  (guarded rows, swizzled store)
            {
                bf16x8 a[2][4];
                #pragma unroll
                for (int rt = 0; rt < 2; ++rt)
                    #pragma unroll
                    for (int kk = 0; kk < 4; ++kk)
                        a[rt][kk] = *(const bf16x8*)(hB0 + swz(rt*16 + l15, kk*64 + l4*16));
                #pragma unroll
                for (int ntg = 0; ntg < 2; ++ntg) {
                    f32x4 acc0 = {b0v[ntg],b0v[ntg],b0v[ntg],b0v[ntg]};
                    f32x4 acc1 = acc0;
                    #pragma unroll
                    for (int kk = 0; kk < 4; ++kk) {
                        acc0 = __builtin_amdgcn_mfma_f32_16x16x32_bf16(a[0][kk], wfB[ntg][kk], acc0, 0,0,0);
                        acc1 = __builtin_amdgcn_mfma_f32_16x16x32_bf16(a[1][kk], wfB[ntg][kk], acc1, 0,0,0);
                    }
                    int col = colb + ntg*16 + l15;
                    #pragma unroll
                    for (int reg = 0; reg < 4; ++reg) {
                        int ra = r0 + l4*4 + reg, rb = r0 + 16 + l4*4 + reg;
                        if (ra < fqc) *(u16*)((char*)fpl + fswz(ra, col)) = f2bf_hw(acc0[reg]);
                        if (rb < fqc) *(u16*)((char*)fpl + fswz(rb, col)) = f2bf_hw(acc1[reg]);
                    }
                }
            }
            __syncthreads();
        }
    }
    __builtin_amdgcn_sched_barrier(0);   // keep Wb/Wo frag loads AFTER prologue

    // ---- main weight fragments ----
    bf16x8 wfrag[2][2][4], wofrag[4];
    {
        const bf16x8* wb = (const bf16x8*)(Wprep + OFF_WB);
        #pragma unroll
        for (int layer = 0; layer < 2; ++layer)
            #pragma unroll
            for (int ntg = 0; ntg < 2; ++ntg)
                #pragma unroll
                for (int kk = 0; kk < 4; ++kk)
                    wfrag[layer][ntg][kk] = wb[(((wid*2+layer)*2+ntg)*4+kk)*64 + l];
        const bf16x8* wo = (const bf16x8*)(Wprep + OFF_WO);
        #pragma unroll
        for (int kk = 0; kk < 4; ++kk) wofrag[kk] = wo[kk*64 + l];
    }
    float w0c[3][2], bbv[2][2];
    #pragma unroll
    for (int ntg = 0; ntg < 2; ++ntg) {
        int col = colb + ntg*16 + l15;
        w0c[0][ntg] = W0[0*FD+col];
        w0c[1][ntg] = W0[1*FD+col];
        w0c[2][ntg] = W0[2*FD+col];
        bbv[0][ntg] = bb[col]; bbv[1][ntg] = bb[FD+col];
    }
    const float bol = (l15 < 3) ? bo[l15] : 0.f;

    auto do_step = [&](const float* curl, float* nxtl, float sval, int qlo, int qhi) {
        for (int i = tid; i < esz3; i += 256) nxtl[i] = curl[i];
        __syncthreads();

        auto layer0 = [&](char* hAt, int qbase, float (&hc)[2][2][4]) {
            #pragma unroll
            for (int rt = 0; rt < 2; ++rt) {
                int q = qbase + rt*4 + l4; if (q > qhi) q = qhi;
                int qe = (q - elo)*3;
                float nx = X0l[qe], ny = X0l[qe+1], nz = X0l[qe+2];
                float cx[4], cy[4], cz[4];
                #pragma unroll
                for (int k = 0; k < 4; ++k) {
                    int nb = q + k - 2;
                    nb = nb < 0 ? 0 : (nb > NPT-1 ? NPT-1 : nb);
                    int te = (nb - elo)*3;
                    cx[k] = curl[te]   - nx;
                    cy[k] = curl[te+1] - ny;
                    cz[k] = curl[te+2] - nz;
                }
                #pragma unroll
                for (int ntg = 0; ntg < 2; ++ntg) {
                    int col = colb + ntg*16 + l15;
                    float fp = bf2f(*(const u16*)((const char*)fpl + fswz(q - fqlo, col)));
                    #pragma unroll
                    for (int reg = 0; reg < 4; ++reg) {
                        float u = fp + cx[reg]*w0c[0][ntg] + cy[reg]*w0c[1][ntg] + cz[reg]*w0c[2][ntg];
                        u = fmaxf(u, 0.f);
                        hc[rt][ntg][reg] = u;
                        *(u16*)(hAt + swz(rt*16 + l4*4 + reg, col*2)) = f2bf_hw(u);
                    }
                }
            }
        };
        auto layer1 = [&](const char* hAt, char* hBt, float (&hc)[2][2][4]) {
            bf16x8 a[2][4];
            #pragma unroll
            for (int rt = 0; rt < 2; ++rt)
                #pragma unroll
                for (int kk = 0; kk < 4; ++kk)
                    a[rt][kk] = *(const bf16x8*)(hAt + swz(rt*16 + l15, kk*64 + l4*16));
            #pragma unroll
            for (int ntg = 0; ntg < 2; ++ntg) {
                f32x4 acc0 = {bbv[0][ntg],bbv[0][ntg],bbv[0][ntg],bbv[0][ntg]};
                f32x4 acc1 = acc0;
                #pragma unroll
                for (int kk = 0; kk < 4; ++kk) {
                    acc0 = __builtin_amdgcn_mfma_f32_16x16x32_bf16(a[0][kk], wfrag[0][ntg][kk], acc0, 0,0,0);
                    acc1 = __builtin_amdgcn_mfma_f32_16x16x32_bf16(a[1][kk], wfrag[0][ntg][kk], acc1, 0,0,0);
                }
                int col = colb + ntg*16 + l15;
                #pragma unroll
                for (int reg = 0; reg < 4; ++reg) {
                    hc[0][ntg][reg] += fmaxf(acc0[reg], 0.f);
                    hc[1][ntg][reg] += fmaxf(acc1[reg], 0.f);
                    *(u16*)(hBt + swz(l4*4+reg,    col*2)) = f2bf_hw(hc[0][ntg][reg]);
                    *(u16*)(hBt + swz(16+l4*4+reg, col*2)) = f2bf_hw(hc[1][ntg][reg]);
                }
            }
        };
        auto layer2 = [&](const char* hBt, char* hCt, float (&hc)[2][2][4]) {
            bf16x8 a[2][4];
            #pragma unroll
            for (int rt = 0; rt < 2; ++rt)
                #pragma unroll
                for (int kk = 0; kk < 4; ++kk)
                    a[rt][kk] = *(const bf16x8*)(hBt + swz(rt*16 + l15, kk*64 + l4*16));
            #pragma unroll
            for (int ntg = 0; ntg < 2; ++ntg) {
                f32x4 acc0 = {bbv[1][ntg],bbv[1][ntg],bbv[1][ntg],bbv[1][ntg]};
                f32x4 acc1 = acc0;
                #pragma unroll
                for (int kk = 0; kk < 4; ++kk) {
                    acc0 = __builtin_amdgcn_mfma_f32_16x16x32_bf16(a[0][kk], wfrag[1][ntg][kk], acc0, 0,0,0);
                    acc1 = __builtin_amdgcn_mfma_f32_16x16x32_bf16(a[1][kk], wfrag[1][ntg][kk], acc1, 0,0,0);
                }
                int col = colb + ntg*16 + l15;
                #pragma unroll
                for (int reg = 0; reg < 4; ++reg) {
                    float h0 = hc[0][ntg][reg] + fmaxf(acc0[reg], 0.f);
                    float h1 = hc[1][ntg][reg] + fmaxf(acc1[reg], 0.f);
                    *(u16*)(hCt + swz(l4*4+reg,    col*2)) = f2bf_hw(h0);
                    *(u16*)(hCt + swz(16+l4*4+reg, col*2)) = f2bf_hw(h1);
                }
            }
        };

        const int nt_ = (qhi - qlo + 8) >> 3;
        const int ng_ = (nt_ + 1) >> 1;
        for (int g = 0; g < ng_; ++g) {
            const int qb0 = qlo + (g*2)*8;
            const int qb1 = qlo + (g*2+1)*8;
            const bool has1 = (g*2+1) < nt_;
            float hc0[2][2][4], hc1[2][2][4];
            // ---- P0: layer0, both tiles ----
            layer0(hA0, qb0, hc0);
            if (has1) layer0(hA1, qb1, hc1);
            __syncthreads();
            // ---- P1: layer1, both tiles ----
            layer1(hA0, hB0, hc0);
            if (has1) layer1(hA1, hB1, hc1);
            __syncthreads();
            // ---- P2: layer2, both tiles ----
            layer2(hB0, hC0, hc0);
            if (has1) layer2(hB1, hC1, hc1);
            __syncthreads();
            // ---- P3: grad = h@Wo (+bo), all 4 waves (2 per tile) ----
            {
                const int t = wid >> 1, sub = wid & 1;
                const char* hCt = t ? hC1 : hC0;
                const int qb = t ? qb1 : qb0;
                bf16x8 a[4];
                #pragma unroll
                for (int kk = 0; kk < 4; ++kk)
                    a[kk] = *(const bf16x8*)(hCt + swz(sub*16 + l15, kk*64 + l4*16));
                f32x4 acc = {0.f,0.f,0.f,0.f};
                #pragma unroll
                for (int kk = 0; kk < 4; ++kk)
                    acc = __builtin_amdgcn_mfma_f32_16x16x32_bf16(a[kk], wofrag[kk], acc, 0,0,0);
                int q = qb + sub*4 + l4;
                if (l15 < 3 && q <= qhi) {
                    #pragma unroll
                    for (int reg = 0; reg < 4; ++reg) {
                        int nb = q + reg - 2;
                        nb = nb < 0 ? 0 : (nb > NPT-1 ? NPT-1 : nb);
                        atomicAdd(&nxtl[(nb - elo)*3 + l15], sval*(acc[reg] + bol));
                    }
                }
            }
            // no barrier: next P0 writes hA* (last read pre-P1-barrier); hC* reads
            // protected by the following P0/P1-end barriers before next P2 write
        }
        __syncthreads();   // all scatters complete before next step reads nxtl
    };

    const int q1lo = fqlo,                 q1hi = fqhi;
    const int q2lo = (A-7 < 0) ? 0 : A-7,  q2hi = (Bp+8 > NPT-1) ? NPT-1 : Bp+8;
    const int q3lo = (A-4 < 0) ? 0 : A-4,  q3hi = (Bp+5 > NPT-1) ? NPT-1 : Bp+5;
    const int q4lo = (A-1 < 0) ? 0 : A-1,  q4hi = (Bp+2 > NPT-1) ? NPT-1 : Bp+2;

    do_step(X0l, Xal, 0.2f,      q1lo, q1hi);
    do_step(Xal, Xbl, 0.19f,     q2lo, q2hi);
    do_step(Xbl, Xal, 0.1805f,   q3lo, q3hi);
    do_step(Xal, Xbl, 0.171475f, q4lo, q4hi);

    for (int i = tid; i < CHK*3; i += 256)
        out[(gb + A)*3 + i] = Xbl[(A - elo)*3 + i];
}

extern "C" void kernel_launch(void* const* d_in, const int* in_sizes, int n_in,
                              void* d_out, int out_size, void* d_ws, size_t ws_size,
                              hipStream_t stream) {
    const float* pcl = (const float*)d_in[0];
    const float* Wf1 = (const float*)d_in[1];
    const float* bf1 = (const float*)d_in[2];
    const float* Wf2 = (const float*)d_in[3];
    const float* bf2 = (const float*)d_in[4];
    const float* W0  = (const float*)d_in[5];
    const float* b0  = (const float*)d_in[6];
    const float* Wb  = (const float*)d_in[7];
    const float* bb  = (const float*)d_in[8];
    const float* Wo  = (const float*)d_in[9];
    const float* bo  = (const float*)d_in[10];
    float* out = (float*)d_out;

    u16* Wprep = (u16*)d_ws;   // 200 KB

    prep_weights<<<(PREP_TOT+255)/256, 256, 0, stream>>>(Wf2, W0, Wb, Wo, Wprep);
    fused_all<<<GRID, 256, 0, stream>>>(pcl, Wf1, bf1, bf2, W0, b0, bb, bo, Wprep, out);
}